// Round 4
// baseline (769.047 us; speedup 1.0000x reference)
//
#include <hip/hip_runtime.h>
#include <hip/hip_bf16.h>
#include <math.h>

#define FEAT 64
#define SCAN_CHUNK 2048   // elements per scan block (256 thr x 8)

// ---------------------------------------------------------------------------
// CSR build: degree count -> hierarchical exclusive scan -> scatter
// ---------------------------------------------------------------------------
__global__ void zero_kernel(int* __restrict__ p, int n) {
    int i = blockIdx.x * blockDim.x + threadIdx.x;
    if (i < n) p[i] = 0;
}

__global__ void count_kernel(const int* __restrict__ dst, int* __restrict__ deg, int nE) {
    int i = blockIdx.x * blockDim.x + threadIdx.x;
    if (i < nE) atomicAdd(&deg[dst[i]], 1);
}

__global__ __launch_bounds__(256) void scan_sum_kernel(const int* __restrict__ deg,
                                                       int* __restrict__ bsum, int n) {
    __shared__ int sdata[4];
    int base = blockIdx.x * SCAN_CHUNK;
    int sum = 0;
    for (int i = threadIdx.x; i < SCAN_CHUNK; i += 256) {
        int idx = base + i;
        if (idx < n) sum += deg[idx];
    }
    for (int d = 32; d > 0; d >>= 1) sum += __shfl_down(sum, d);
    if ((threadIdx.x & 63) == 0) sdata[threadIdx.x >> 6] = sum;
    __syncthreads();
    if (threadIdx.x == 0) bsum[blockIdx.x] = sdata[0] + sdata[1] + sdata[2] + sdata[3];
}

__global__ void scan_block_kernel(const int* __restrict__ bsum, int* __restrict__ boff, int nb) {
    int tid = threadIdx.x;
    int own = (tid < nb) ? bsum[tid] : 0;
    int v = own;
    for (int d = 1; d < 64; d <<= 1) {
        int t = __shfl_up(v, d);
        if (tid >= d) v += t;
    }
    if (tid < nb) boff[tid] = v - own;
}

__global__ __launch_bounds__(256) void scan_write_kernel(const int* __restrict__ deg,
                                                         const int* __restrict__ boff,
                                                         int* __restrict__ off, int n, int E) {
    __shared__ int sw[8];
    int b = blockIdx.x;
    int t = threadIdx.x;
    int i0 = b * SCAN_CHUNK + t * 8;
    int local[8];
    int s = 0;
#pragma unroll
    for (int j = 0; j < 8; ++j) {
        int idx = i0 + j;
        local[j] = (idx < n) ? deg[idx] : 0;
        s += local[j];
    }
    int lane = t & 63, w = t >> 6;
    int inc = s;
    for (int d = 1; d < 64; d <<= 1) {
        int tt = __shfl_up(inc, d);
        if (lane >= d) inc += tt;
    }
    if (lane == 63) sw[w] = inc;
    __syncthreads();
    if (t == 0) { int r = 0; for (int k = 0; k < 4; ++k) { int v = sw[k]; sw[k] = r; r += v; } }
    __syncthreads();
    int texc = (inc - s) + sw[w] + boff[b];
#pragma unroll
    for (int j = 0; j < 8; ++j) {
        int idx = i0 + j;
        if (idx < n) off[idx] = texc;
        texc += local[j];
    }
    if (b == 0 && t == 0) off[n] = E;
}

__global__ void scatter_kernel(const int* __restrict__ src, const int* __restrict__ dst,
                               const int* __restrict__ off, int* __restrict__ cursor,
                               int* __restrict__ csr_src, int nE) {
    int i = blockIdx.x * blockDim.x + threadIdx.x;
    if (i < nE) {
        int d = dst[i];
        int p = atomicAdd(&cursor[d], 1);
        csr_src[off[d] + p] = src[i];
    }
}

// ---------------------------------------------------------------------------
// Fold Wr+Ws -> Wc and bl+bs -> bias for all 3 layers (SALU has no float add)
// ---------------------------------------------------------------------------
__global__ void prep_kernel(const float* __restrict__ Wr0, const float* __restrict__ Ws0,
                            const float* __restrict__ bl0, const float* __restrict__ bs0,
                            const float* __restrict__ Wr1, const float* __restrict__ Ws1,
                            const float* __restrict__ bl1, const float* __restrict__ bs1,
                            const float* __restrict__ Wr2, const float* __restrict__ Ws2,
                            const float* __restrict__ bl2, const float* __restrict__ bs2,
                            float* __restrict__ wc, float* __restrict__ bias) {
    int i = blockIdx.x * blockDim.x + threadIdx.x;
    if (i < 3 * FEAT * FEAT) {
        int li = i >> 12, j = i & 4095;
        const float* Wr = (li == 0) ? Wr0 : (li == 1) ? Wr1 : Wr2;
        const float* Ws = (li == 0) ? Ws0 : (li == 1) ? Ws1 : Ws2;
        wc[i] = Wr[j] + Ws[j];
    }
    if (i < 3 * FEAT) {
        int li = i >> 6, j = i & 63;
        const float* bl = (li == 0) ? bl0 : (li == 1) ? bl1 : bl2;
        const float* bs = (li == 0) ? bs0 : (li == 1) ? bs1 : bs2;
        bias[i] = bl[j] + bs[j];
    }
}

// ---------------------------------------------------------------------------
// Max-aggregation: one 16-lane group per node, inner loop unrolled x4.
// ---------------------------------------------------------------------------
__device__ __forceinline__ float4 max4(float4 a, float4 b) {
    return make_float4(fmaxf(a.x, b.x), fmaxf(a.y, b.y), fmaxf(a.z, b.z), fmaxf(a.w, b.w));
}

__global__ __launch_bounds__(256) void agg_kernel(const float* __restrict__ h,
                                                  const int* __restrict__ off,
                                                  const int* __restrict__ csr_src,
                                                  float* __restrict__ agg, int nNodes) {
    int gid = blockIdx.x * blockDim.x + threadIdx.x;
    int n = gid >> 4;
    int q = gid & 15;
    if (n >= nNodes) return;

    int e0 = off[n], e1 = off[n + 1];
    const float NEG = -INFINITY;
    float4 acc0 = make_float4(NEG, NEG, NEG, NEG);
    float4 acc1 = acc0;
    int e = e0;
    for (; e + 4 <= e1; e += 4) {
        int s0 = csr_src[e], s1 = csr_src[e + 1], s2 = csr_src[e + 2], s3 = csr_src[e + 3];
        float4 v0 = *(const float4*)&h[(size_t)s0 * FEAT + q * 4];
        float4 v1 = *(const float4*)&h[(size_t)s1 * FEAT + q * 4];
        float4 v2 = *(const float4*)&h[(size_t)s2 * FEAT + q * 4];
        float4 v3 = *(const float4*)&h[(size_t)s3 * FEAT + q * 4];
        acc0 = max4(acc0, max4(v0, v1));
        acc1 = max4(acc1, max4(v2, v3));
    }
    for (; e < e1; ++e) {
        int s0 = csr_src[e];
        float4 v0 = *(const float4*)&h[(size_t)s0 * FEAT + q * 4];
        acc0 = max4(acc0, v0);
    }
    float4 acc = max4(acc0, acc1);
    if (e1 == e0) acc = make_float4(0.f, 0.f, 0.f, 0.f);
    *(float4*)&agg[(size_t)n * FEAT + q * 4] = acc;
}

// ---------------------------------------------------------------------------
// Transform: out = relu(agg @ Wl^T + h @ Wc^T + bias), Wc = Wr+Ws.
// lane = node (64 nodes/wave); wave computes 32 output features (f-split x2).
// Weights are wave-uniform -> SGPR operand of v_fmac; node rows in VGPRs.
// ---------------------------------------------------------------------------
__global__ __launch_bounds__(256) void transform_kernel(const float* __restrict__ h,
                                                        const float* __restrict__ agg,
                                                        const float* __restrict__ Wl,
                                                        const float* __restrict__ Wc,
                                                        const float* __restrict__ bias,
                                                        float* __restrict__ out, int nNodes) {
    int wid  = (blockIdx.x * blockDim.x + threadIdx.x) >> 6;   // global wave id
    int lane = threadIdx.x & 63;
    int tile = wid >> 1;
    int fh   = (wid & 1) * 32;
    int nTiles = (nNodes + 63) >> 6;
    if (tile >= nTiles) return;

    int n  = tile * 64 + lane;
    int nc = (n < nNodes) ? n : (nNodes - 1);          // clamped for loads
    const float* __restrict__ ar = agg + (size_t)nc * FEAT;
    const float* __restrict__ hr = h   + (size_t)nc * FEAT;

    float acc[32];
#pragma unroll
    for (int f = 0; f < 32; ++f) acc[f] = bias[fh + f];

#pragma unroll 2
    for (int kc = 0; kc < FEAT; kc += 16) {
        float ra[16], rh[16];
#pragma unroll
        for (int j = 0; j < 16; j += 4) {
            float4 va = *(const float4*)(ar + kc + j);
            float4 vh = *(const float4*)(hr + kc + j);
            ra[j] = va.x; ra[j+1] = va.y; ra[j+2] = va.z; ra[j+3] = va.w;
            rh[j] = vh.x; rh[j+1] = vh.y; rh[j+2] = vh.z; rh[j+3] = vh.w;
        }
#pragma unroll
        for (int f = 0; f < 32; ++f) {
            const float* __restrict__ wlr = Wl + (size_t)(fh + f) * FEAT + kc;
            const float* __restrict__ wcr = Wc + (size_t)(fh + f) * FEAT + kc;
#pragma unroll
            for (int j = 0; j < 16; ++j) {
                acc[f] = fmaf(ra[j], wlr[j], acc[f]);
                acc[f] = fmaf(rh[j], wcr[j], acc[f]);
            }
        }
    }

    if (n < nNodes) {
        float* __restrict__ orow = out + (size_t)n * FEAT + fh;
#pragma unroll
        for (int f = 0; f < 32; f += 4) {
            float4 v = make_float4(fmaxf(acc[f],     0.f), fmaxf(acc[f + 1], 0.f),
                                   fmaxf(acc[f + 2], 0.f), fmaxf(acc[f + 3], 0.f));
            *(float4*)(orow + f) = v;
        }
    }
}

// ---------------------------------------------------------------------------
extern "C" void kernel_launch(void* const* d_in, const int* in_sizes, int n_in,
                              void* d_out, int out_size, void* d_ws, size_t ws_size,
                              hipStream_t stream) {
    const float* x   = (const float*)d_in[0];
    const int* eidx  = (const int*)d_in[1];
    const int N  = in_sizes[0] / FEAT;
    const int E  = in_sizes[1] / 2;
    const int* src = eidx;
    const int* dst = eidx + E;

    const float* Wl[3]; const float* bl[3]; const float* Wr[3];
    const float* Ws[3]; const float* bs[3];
    for (int li = 0; li < 3; ++li) {
        Wl[li] = (const float*)d_in[2 + 5 * li + 0];
        bl[li] = (const float*)d_in[2 + 5 * li + 1];
        Wr[li] = (const float*)d_in[2 + 5 * li + 2];
        Ws[li] = (const float*)d_in[2 + 5 * li + 3];
        bs[li] = (const float*)d_in[2 + 5 * li + 4];
    }

    auto align256 = [](size_t v) { return (v + 255) & ~(size_t)255; };
    char* ws = (char*)d_ws;
    int* off      = (int*)ws;  ws += align256((size_t)(N + 1) * 4);
    int* cursor   = (int*)ws;  ws += align256((size_t)N * 4);
    int* bsum     = (int*)ws;  ws += align256(64 * 4);
    int* boff     = (int*)ws;  ws += align256(64 * 4);
    float* wcbuf  = (float*)ws; ws += align256(3 * FEAT * FEAT * 4);
    float* biasbuf= (float*)ws; ws += align256(3 * FEAT * 4);
    int* csr_src  = (int*)ws;  ws += align256((size_t)E * 4);
    float* aggbuf = (float*)ws; ws += align256((size_t)N * FEAT * 4);
    float* h1     = (float*)ws; ws += align256((size_t)N * FEAT * 4);
    float* h2     = (float*)ws; ws += align256((size_t)N * FEAT * 4);

    const int TB = 256;
    int eBlocks = (E + TB - 1) / TB;
    int nBlocks = (N + TB - 1) / TB;
    int nb = (N + SCAN_CHUNK - 1) / SCAN_CHUNK;

    // ---- CSR build + weight fold ----
    zero_kernel<<<nBlocks, TB, 0, stream>>>(cursor, N);
    count_kernel<<<eBlocks, TB, 0, stream>>>(dst, cursor, E);
    scan_sum_kernel<<<nb, TB, 0, stream>>>(cursor, bsum, N);
    scan_block_kernel<<<1, 64, 0, stream>>>(bsum, boff, nb);
    scan_write_kernel<<<nb, TB, 0, stream>>>(cursor, boff, off, N, E);
    zero_kernel<<<nBlocks, TB, 0, stream>>>(cursor, N);
    scatter_kernel<<<eBlocks, TB, 0, stream>>>(src, dst, off, cursor, csr_src, E);
    prep_kernel<<<(3 * FEAT * FEAT + TB - 1) / TB, TB, 0, stream>>>(
        Wr[0], Ws[0], bl[0], bs[0], Wr[1], Ws[1], bl[1], bs[1],
        Wr[2], Ws[2], bl[2], bs[2], wcbuf, biasbuf);

    int aggBlocks = (N * 16 + TB - 1) / TB;
    int nTiles = (N + 63) / 64;
    int trfBlocks = (nTiles * 2 + 3) / 4;     // 2 waves per tile, 4 waves per block

    agg_kernel<<<aggBlocks, TB, 0, stream>>>(x, off, csr_src, aggbuf, N);
    transform_kernel<<<trfBlocks, TB, 0, stream>>>(x, aggbuf, Wl[0], wcbuf + 0 * 4096,
                                                   biasbuf + 0 * 64, h1, N);
    agg_kernel<<<aggBlocks, TB, 0, stream>>>(h1, off, csr_src, aggbuf, N);
    transform_kernel<<<trfBlocks, TB, 0, stream>>>(h1, aggbuf, Wl[1], wcbuf + 1 * 4096,
                                                   biasbuf + 1 * 64, h2, N);
    agg_kernel<<<aggBlocks, TB, 0, stream>>>(h2, off, csr_src, aggbuf, N);
    transform_kernel<<<trfBlocks, TB, 0, stream>>>(h2, aggbuf, Wl[2], wcbuf + 2 * 4096,
                                                   biasbuf + 2 * 64, (float*)d_out, N);
}